// Round 12
// baseline (374.243 us; speedup 1.0000x reference)
//
#include <hip/hip_runtime.h>

typedef unsigned short u16;
typedef unsigned int   u32;
typedef __attribute__((ext_vector_type(8))) _Float16 half8;
typedef __attribute__((ext_vector_type(4))) float f32x4;
typedef __attribute__((ext_vector_type(2))) float f32x2;
typedef __attribute__((ext_vector_type(4))) u32   u32x4;
typedef __attribute__((ext_vector_type(4))) unsigned short u16x4;

#define MFMAH __builtin_amdgcn_mfma_f32_16x16x32_f16

// W fp16 storage: rows 0-511 = Wf, 512-1023 = Wg, 1024-1535 = Wh, k-contig.
__device__ u16 W16[786432];

__device__ __forceinline__ u16 f2h(float f) {            // fp32 -> fp16 rne
  _Float16 h = (_Float16)f;
  union { _Float16 hh; u16 u; } cv; cv.hh = h; return cv.u;
}
__device__ __forceinline__ u32 pkh(float a, float b) {   // two rne halves packed
  return (u32)f2h(a) | ((u32)f2h(b) << 16);
}
__device__ __forceinline__ void gload16(const void* g, void* l) {
  __builtin_amdgcn_global_load_lds(
      (const __attribute__((address_space(1))) void*)g,
      (__attribute__((address_space(3))) void*)l, 16, 0, 0);
}

// ---------------------------------------------------------------------------
// prep_w: W fp32 -> fp16 (rne)
// ---------------------------------------------------------------------------
__global__ __launch_bounds__(256)
void prep_w(const float* __restrict__ Wf, const float* __restrict__ Wg,
            const float* __restrict__ Wh)
{
  const int r = blockIdx.x;                    // 0..1535
  const int k = threadIdx.x * 2;
  const float* src = (r < 512) ? (Wf + (size_t)r * 512)
                   : (r < 1024) ? (Wg + (size_t)(r - 512) * 512)
                                : (Wh + (size_t)(r - 1024) * 512);
  f32x2 v = *(const f32x2*)(src + k);
  *(u32*)(W16 + (size_t)r * 512 + k) = pkh(v[0], v[1]);
}

// ---------------------------------------------------------------------------
// prep_x: x[512][65536] fp32 -> xT[65536][512] fp16 (rne).
// ---------------------------------------------------------------------------
__global__ __launch_bounds__(256)
void prep_x(const float* __restrict__ x, u16* __restrict__ x16)
{
  __shared__ float tile[64 * 256];             // 64 KB
  const int bk = blockIdx.x & 7, bn = blockIdx.x >> 3;
  const int t = threadIdx.x;
  const int cw = (t & 63) * 4, r0 = (t >> 6) * 16;
#pragma unroll
  for (int it = 0; it < 16; ++it) {
    const int r = r0 + it;
    *(f32x4*)&tile[r * 256 + cw] =
        *(const f32x4*)(x + (size_t)(bk * 64 + r) * 65536 + (size_t)bn * 256 + cw);
  }
  __syncthreads();
  u32 w[32];
#pragma unroll
  for (int q = 0; q < 32; ++q)
    w[q] = pkh(tile[(2 * q) * 256 + t], tile[(2 * q + 1) * 256 + t]);
  const size_t ob = (size_t)(bn * 256 + t) * 512 + bk * 64;
#pragma unroll
  for (int c4 = 0; c4 < 8; ++c4)
    *(u32x4*)(x16 + ob + c4 * 8) = (u32x4){w[4*c4], w[4*c4+1], w[4*c4+2], w[4*c4+3]};
}

// ---------------------------------------------------------------------------
// conv_fgh (A-resident): block owns one 128-row W-stripe, kept ENTIRELY in
// LDS (128 rows x 512 k fp16 = 128 KB, slot^(row&7) bank swizzle); streams 8
// panels of 128 x-cols with a 2x8 KB B double-buffer -> 1 gload/thread per
// K-step, per-step barrier drains a load issued a full step earlier.
// 512 thr = 8 waves (2M x 4N), wave tile 64x32, acc[4][2], 8 MFMA/step.
// Grid 768 = 8 XCD x (8 panel-groups x 12 stripes, stripe-inner for L2 reuse).
// Stripes: s=0..11, cls=s>>2 (0:f, 1:g sigma-read -> gT, 2:h), mloc=s&3.
// ---------------------------------------------------------------------------
__global__ __launch_bounds__(512, 2)
void conv_fgh(const u16* __restrict__ x16, u16* __restrict__ fb,
              u16* __restrict__ gTb, u16* __restrict__ hb)
{
  __shared__ u16 lds[73728];                   // 144 KB: A 128K @0, B 2x8K @128K
  char* const L = (char*)lds;
  const int bid = blockIdx.x;
  const int xcd = bid & 7, idx = bid >> 3;     // 96 per XCD
  const int p = xcd * 8 + idx / 12;            // panel-group 0..63 (1024 cols)
  const int s = idx % 12;
  const int cls = s >> 2, mloc = s & 3;
  const bool gmode = (cls == 1);
  const int t = threadIdx.x, lane = t & 63, wid = t >> 6;
  const int wr = wid >> 2, wc = wid & 3, lr = lane & 15, lq = lane >> 4;

  // ---- stage A resident: row r local (0..127), 64 slots of 16B, swizzled
#pragma unroll
  for (int q = 0; q < 16; ++q) {
    const int r = q * 8 + wid;
    const int wrow = cls * 512 + mloc * 128 + r;
    const int k = ((lane ^ (r & 7)) << 3);
    gload16(W16 + (size_t)wrow * 512 + k, L + r * 1024 + lane * 16);
  }

  // ---- B staging mapping: col = t>>2 (0..127), slot = t&3, proven swizzle
  const int bcol = t >> 2, bslot = t & 3;
  const int bko = ((bslot ^ ((bcol >> 1) & 3)) << 3);

  // ---- fragment read offsets
  int offArow[4], rowA7[4];
#pragma unroll
  for (int mi = 0; mi < 4; ++mi) {
    const int rowA = wr * 64 + mi * 16 + lr;   // 0..127
    offArow[mi] = rowA * 1024;
    rowA7[mi] = rowA & 7;
  }
  int offB[2];
#pragma unroll
  for (int ni = 0; ni < 2; ++ni) {
    const int colB = wc * 32 + ni * 16 + lr;   // 0..127
    offB[ni] = 131072 + colB * 64 + ((lq ^ ((colB >> 1) & 3)) << 4);
  }

  __syncthreads();                             // A resident + visible

#pragma unroll 1
  for (int pi = 0; pi < 8; ++pi) {
    const int jg = p * 1024 + pi * 128 + bcol;
    const size_t bxr = gmode ? ((size_t)(jg & 255) * 256 + (jg >> 8)) : (size_t)jg;
    // panel prologue: stage B[0] into buf0
    gload16(x16 + bxr * 512 + bko, L + 131072 + t * 16);
    __syncthreads();

    f32x4 acc[4][2] = {};
#pragma unroll 1
    for (int T = 0; T < 16; ++T) {
      if (T < 15)
        gload16(x16 + bxr * 512 + (T + 1) * 32 + bko,
                L + 131072 + ((T + 1) & 1) * 8192 + t * 16);
      const int bb = (T & 1) << 13;
      const int t4 = T * 4;
      half8 a[4], b[2];
#pragma unroll
      for (int mi = 0; mi < 4; ++mi)
        a[mi] = *(const half8*)(L + offArow[mi] + (((t4 + lq) ^ rowA7[mi]) << 4));
#pragma unroll
      for (int ni = 0; ni < 2; ++ni)
        b[ni] = *(const half8*)(L + offB[ni] + bb);
#pragma unroll
      for (int mi = 0; mi < 4; ++mi)
#pragma unroll
        for (int ni = 0; ni < 2; ++ni)
          acc[mi][ni] = MFMAH(a[mi], b[ni], acc[mi][ni], 0, 0, 0);
      __syncthreads();
    }

    // ---- panel epilogue
    u16* dst = (cls == 0) ? fb : (cls == 1) ? gTb : hb;
    const int rbase = mloc * 128 + wr * 64;
    const int cb0 = p * 1024 + pi * 128 + wc * 32;
#pragma unroll
    for (int mi = 0; mi < 4; ++mi)
#pragma unroll
      for (int ni = 0; ni < 2; ++ni) {
        const int r0 = rbase + mi * 16 + lq * 4;
        const int cc = cb0 + ni * 16 + lr;
#pragma unroll
        for (int r = 0; r < 4; ++r)
          dst[(size_t)(r0 + r) * 65536 + cc] = f2h(acc[mi][ni][r]);
      }
    // next panel's prologue overwrites buf0 (last read at T=14, safe) and
    // the epilogue touched only registers -> no extra barrier needed before
    // the gload, but the gload targets buf0 which this panel's T=15 did NOT
    // read; T=15 sync already passed. OK.
  }
}

// ---------------------------------------------------------------------------
// scores: per (c, jt): S = f[c](256 x 256) @ gT[c][jt](128 x 256)^T, fp16.
// Block owns FULL softmax columns -> writes normalized PT[c][j][i] fp16.
// ---------------------------------------------------------------------------
__global__ __launch_bounds__(512)
void scores_kernel(const u16* __restrict__ fb, const u16* __restrict__ gTb,
                   u16* __restrict__ Pt)
{
  __shared__ u16 sA[8192];                     // 16 KB: 256 rows x 32 k
  __shared__ u16 sB[4096];                     // 8 KB: 128 rows x 32 k
  __shared__ float cmax[512], csum[512];
  const int bid = blockIdx.x;
  const int xcd = bid & 7, i2 = bid >> 3;      // 1024 = 8 x (64 c x 2 jt)
  const int c = xcd * 64 + (i2 >> 1), jt = i2 & 1;
  const size_t cb = (size_t)c * 65536;
  const int t = threadIdx.x, lane = t & 63, wid = t >> 6;
  const int wr = wid >> 1, wc = wid & 1, lr = lane & 15, lq = lane >> 4;

  const int arow0 = t >> 2, arow1 = 128 + (t >> 2);
  const int aks0 = (((t & 3) ^ ((arow0 >> 1) & 3)) << 3);
  const int aks1 = (((t & 3) ^ ((arow1 >> 1) & 3)) << 3);
  const int brow = t >> 2;
  const int bks  = (((t & 3) ^ ((brow >> 1) & 3)) << 3);

  int offA[4], offB[4];
#pragma unroll
  for (int mi = 0; mi < 4; ++mi) {
    const int rowA = wr * 64 + mi * 16 + lr;
    offA[mi] = rowA * 32 + ((lq ^ ((rowA >> 1) & 3)) << 3);
  }
#pragma unroll
  for (int ni = 0; ni < 4; ++ni) {
    const int rowB = wc * 64 + ni * 16 + lr;
    offB[ni] = rowB * 32 + ((lq ^ ((rowB >> 1) & 3)) << 3);
  }

  f32x4 acc[4][4] = {};

  for (int k0 = 0; k0 < 256; k0 += 32) {
    gload16(fb + cb + (size_t)arow0 * 256 + k0 + aks0, (char*)sA + t * 16);
    gload16(fb + cb + (size_t)arow1 * 256 + k0 + aks1, (char*)sA + 8192 + t * 16);
    gload16(gTb + cb + (size_t)(jt * 128 + brow) * 256 + k0 + bks, (char*)sB + t * 16);
    __syncthreads();
    half8 a[4], b[4];
#pragma unroll
    for (int mi = 0; mi < 4; ++mi) a[mi] = *(const half8*)(sA + offA[mi]);
#pragma unroll
    for (int ni = 0; ni < 4; ++ni) b[ni] = *(const half8*)(sB + offB[ni]);
#pragma unroll
    for (int mi = 0; mi < 4; ++mi)
#pragma unroll
      for (int ni = 0; ni < 4; ++ni)
        acc[mi][ni] = MFMAH(a[mi], b[ni], acc[mi][ni], 0, 0, 0);
    __syncthreads();
  }

  // ---- full-column softmax over i (rows span wr,mi,lq,r), per column
#pragma unroll
  for (int ni = 0; ni < 4; ++ni) {
    const int col = wc * 64 + ni * 16 + lr;
    float m = -3.4e38f;
#pragma unroll
    for (int mi = 0; mi < 4; ++mi) {
      f32x4 a = acc[mi][ni];
      m = fmaxf(m, fmaxf(fmaxf(a[0], a[1]), fmaxf(a[2], a[3])));
    }
    m = fmaxf(m, __shfl_xor(m, 16));
    m = fmaxf(m, __shfl_xor(m, 32));
    cmax[wr * 128 + col] = m;
  }
  __syncthreads();
#pragma unroll
  for (int ni = 0; ni < 4; ++ni) {
    const int col = wc * 64 + ni * 16 + lr;
    const float M = fmaxf(fmaxf(cmax[col], cmax[128 + col]),
                          fmaxf(cmax[256 + col], cmax[384 + col]));
    float s = 0.f;
#pragma unroll
    for (int mi = 0; mi < 4; ++mi)
#pragma unroll
      for (int r = 0; r < 4; ++r) {
        float e = __expf(acc[mi][ni][r] - M);
        acc[mi][ni][r] = e; s += e;
      }
    s += __shfl_xor(s, 16);
    s += __shfl_xor(s, 32);
    csum[wr * 128 + col] = s;
  }
  __syncthreads();
#pragma unroll
  for (int ni = 0; ni < 4; ++ni) {
    const int col = wc * 64 + ni * 16 + lr;
    const float rs = 1.f / (csum[col] + csum[128 + col] + csum[256 + col] + csum[384 + col]);
    const int j = jt * 128 + col;
#pragma unroll
    for (int mi = 0; mi < 4; ++mi) {
      u16x4 w = { f2h(acc[mi][ni][0] * rs), f2h(acc[mi][ni][1] * rs),
                  f2h(acc[mi][ni][2] * rs), f2h(acc[mi][ni][3] * rs) };
      *(u16x4*)(Pt + cb + (size_t)j * 256 + wr * 64 + mi * 16 + lq * 4) = w;
    }
  }
}

// ---------------------------------------------------------------------------
// attn: out[c,a,j] = x[c,a,j] + sum_i h[c,a,i] * PT[c,j,i]. fp16 MFMA.
// 256x128 tile (2 blocks/channel), 512 thr = 8 waves (4M x 2N).
// ---------------------------------------------------------------------------
__global__ __launch_bounds__(512, 4)
void attn_kernel(const u16* __restrict__ hb, const u16* __restrict__ Pt,
                 const float* __restrict__ x, float* __restrict__ out)
{
  __shared__ u16 sA[8192], sB[4096];           // 16 KB + 8 KB
  const int bid = blockIdx.x;
  const int xcd = bid & 7, i2 = bid >> 3;      // 1024 = 8 x (64 c x 2 tn)
  const int c = xcd * 64 + (i2 >> 1), tn = i2 & 1;
  const size_t cb = (size_t)c * 65536;
  const int t = threadIdx.x, lane = t & 63, wid = t >> 6;
  const int wr = wid >> 1, wc = wid & 1, lr = lane & 15, lq = lane >> 4;

  const int ar0 = t >> 2, ar1 = 128 + (t >> 2);
  const int aks0 = (((t & 3) ^ ((ar0 >> 1) & 3)) << 3);
  const int aks1 = (((t & 3) ^ ((ar1 >> 1) & 3)) << 3);
  const int br = t >> 2;
  const int bks = (((t & 3) ^ ((br >> 1) & 3)) << 3);

  int offA[4], offB[4];
#pragma unroll
  for (int mi = 0; mi < 4; ++mi) {
    const int rowA = wr * 64 + mi * 16 + lr;   // 0..255
    offA[mi] = rowA * 32 + ((lq ^ ((rowA >> 1) & 3)) << 3);
  }
#pragma unroll
  for (int ni = 0; ni < 4; ++ni) {
    const int rowB = wc * 64 + ni * 16 + lr;   // 0..127
    offB[ni] = rowB * 32 + ((lq ^ ((rowB >> 1) & 3)) << 3);
  }

  f32x4 acc[4][4] = {};

  for (int k0 = 0; k0 < 256; k0 += 32) {
    gload16(hb + cb + (size_t)ar0 * 256 + k0 + aks0, (char*)sA + t * 16);
    gload16(hb + cb + (size_t)ar1 * 256 + k0 + aks1, (char*)sA + 8192 + t * 16);
    gload16(Pt + cb + (size_t)(tn * 128 + br) * 256 + k0 + bks, (char*)sB + t * 16);
    __syncthreads();
    half8 a[4], b[4];
#pragma unroll
    for (int mi = 0; mi < 4; ++mi) a[mi] = *(const half8*)(sA + offA[mi]);
#pragma unroll
    for (int ni = 0; ni < 4; ++ni) b[ni] = *(const half8*)(sB + offB[ni]);
#pragma unroll
    for (int mi = 0; mi < 4; ++mi)
#pragma unroll
      for (int ni = 0; ni < 4; ++ni)
        acc[mi][ni] = MFMAH(a[mi], b[ni], acc[mi][ni], 0, 0, 0);
    __syncthreads();
  }

  const float* Xc = x + cb;
  float* Oc = out + cb;
  const int rbase = wr * 64;                   // rows 0..255
  const int cbase = tn * 128 + wc * 64;        // cols 0..255
#pragma unroll
  for (int mi = 0; mi < 4; ++mi)
#pragma unroll
    for (int ni = 0; ni < 4; ++ni) {
      const int r0 = rbase + mi * 16 + lq * 4, cc = cbase + ni * 16 + lr;
#pragma unroll
      for (int r = 0; r < 4; ++r) {
        const size_t idx = (size_t)(r0 + r) * 256 + cc;
        Oc[idx] = Xc[idx] + acc[mi][ni][r];
      }
    }
}

// ---------------------------------------------------------------------------
extern "C" void kernel_launch(void* const* d_in, const int* in_sizes, int n_in,
                              void* d_out, int out_size, void* d_ws, size_t ws_size,
                              hipStream_t stream)
{
  (void)in_sizes; (void)n_in; (void)out_size; (void)ws_size;
  const float* x  = (const float*)d_in[0];
  const float* Wf = (const float*)d_in[1];
  const float* Wg = (const float*)d_in[2];
  const float* Wh = (const float*)d_in[3];
  float* out = (float*)d_out;
  char*  ws  = (char*)d_ws;

  // ws: [x16 64Mi][gT16 64Mi][h16 64Mi]; f16 lives in d_out's first 64 MiB.
  u16* x16  = (u16*)ws;
  u16* gT16 = (u16*)(ws + 67108864);
  u16* h16  = (u16*)(ws + 134217728);
  u16* f16  = (u16*)d_out;
  u16* Pt   = x16;   // PT overwrites x16 after conv_fgh

  dim3 blk(256, 1, 1);
  prep_w       <<<dim3(1536, 1, 1), blk, 0, stream>>>(Wf, Wg, Wh);
  prep_x       <<<dim3(2048, 1, 1), blk, 0, stream>>>(x, x16);
  conv_fgh     <<<dim3(768, 1, 1), dim3(512, 1, 1), 0, stream>>>(x16, f16, gT16, h16);
  scores_kernel<<<dim3(1024, 1, 1), dim3(512, 1, 1), 0, stream>>>(f16, gT16, Pt);
  attn_kernel  <<<dim3(1024, 1, 1), dim3(512, 1, 1), 0, stream>>>(h16, Pt, x, out);
}

// Round 13
// 357.266 us; speedup vs baseline: 1.0475x; 1.0475x over previous
//
#include <hip/hip_runtime.h>

typedef unsigned short u16;
typedef unsigned int   u32;
typedef __attribute__((ext_vector_type(8))) _Float16 half8;
typedef __attribute__((ext_vector_type(4))) float f32x4;
typedef __attribute__((ext_vector_type(2))) float f32x2;
typedef __attribute__((ext_vector_type(4))) u32   u32x4;
typedef __attribute__((ext_vector_type(4))) unsigned short u16x4;

#define MFMAH __builtin_amdgcn_mfma_f32_16x16x32_f16

// W fp16 storage: rows 0-511 = Wf, 512-1023 = Wg, 1024-1535 = Wh, k-contig.
__device__ u16 W16[786432];

__device__ __forceinline__ u16 f2h(float f) {            // fp32 -> fp16 rne
  _Float16 h = (_Float16)f;
  union { _Float16 hh; u16 u; } cv; cv.hh = h; return cv.u;
}
__device__ __forceinline__ u32 pkh(float a, float b) {   // two rne halves packed
  return (u32)f2h(a) | ((u32)f2h(b) << 16);
}
__device__ __forceinline__ void gload16(const void* g, void* l) {
  __builtin_amdgcn_global_load_lds(
      (const __attribute__((address_space(1))) void*)g,
      (__attribute__((address_space(3))) void*)l, 16, 0, 0);
}

// ---------------------------------------------------------------------------
// prep_w: W fp32 -> fp16 (rne)
// ---------------------------------------------------------------------------
__global__ __launch_bounds__(256)
void prep_w(const float* __restrict__ Wf, const float* __restrict__ Wg,
            const float* __restrict__ Wh)
{
  const int r = blockIdx.x;                    // 0..1535
  const int k = threadIdx.x * 2;
  const float* src = (r < 512) ? (Wf + (size_t)r * 512)
                   : (r < 1024) ? (Wg + (size_t)(r - 512) * 512)
                                : (Wh + (size_t)(r - 1024) * 512);
  f32x2 v = *(const f32x2*)(src + k);
  *(u32*)(W16 + (size_t)r * 512 + k) = pkh(v[0], v[1]);
}

// ---------------------------------------------------------------------------
// prep_x: x[512][65536] fp32 -> xT[65536][512] fp16 (rne).
// ---------------------------------------------------------------------------
__global__ __launch_bounds__(256)
void prep_x(const float* __restrict__ x, u16* __restrict__ x16)
{
  __shared__ float tile[64 * 256];             // 64 KB
  const int bk = blockIdx.x & 7, bn = blockIdx.x >> 3;
  const int t = threadIdx.x;
  const int cw = (t & 63) * 4, r0 = (t >> 6) * 16;
#pragma unroll
  for (int it = 0; it < 16; ++it) {
    const int r = r0 + it;
    *(f32x4*)&tile[r * 256 + cw] =
        *(const f32x4*)(x + (size_t)(bk * 64 + r) * 65536 + (size_t)bn * 256 + cw);
  }
  __syncthreads();
  u32 w[32];
#pragma unroll
  for (int q = 0; q < 32; ++q)
    w[q] = pkh(tile[(2 * q) * 256 + t], tile[(2 * q + 1) * 256 + t]);
  const size_t ob = (size_t)(bn * 256 + t) * 512 + bk * 64;
#pragma unroll
  for (int c4 = 0; c4 < 8; ++c4)
    *(u32x4*)(x16 + ob + c4 * 8) = (u32x4){w[4*c4], w[4*c4+1], w[4*c4+2], w[4*c4+3]};
}

// ---------------------------------------------------------------------------
// conv_fgh: fused fp16 GEMM, M=1536 ([f;g;h] = W @ x). 128x128 tile, BK=64,
// 256 thr / 4 waves (2x2), per-wave 64x64, 32 MFMA + 16 ds_read per step,
// only 8 K-steps (half the barrier drains of BK=32 — the one cost term the
// schedule experiments couldn't touch).
// LDS 32 KB single-buffered; loads -> __syncthreads -> reads (zero-conflict
// discipline, r12 lesson: overlapping DMA writes with ds_reads = conflicts).
// Rows 128 B, source swizzle slot^(row&7); matching XOR on frag reads.
// tm 0-3: f, 4-7: g (sigma B rows -> writes gT[c][j][k]), 8-11: h.
// Grid 6144 = 8 XCD x (64 tn x 12 tm), stripe-inner for B L2 reuse.
// ---------------------------------------------------------------------------
__global__ __launch_bounds__(256)
void conv_fgh(const u16* __restrict__ x16, u16* __restrict__ fb,
              u16* __restrict__ gTb, u16* __restrict__ hb)
{
  __shared__ u16 sA[8192], sB[8192];           // 16 KB each: 128 rows x 64 k
  const int bid = blockIdx.x;
  const int xcd = bid & 7, idx = bid >> 3;     // 6144 = 8 XCD x (64 tn x 12 tm)
  const int tn = xcd * 64 + idx / 12;
  const int tm = idx % 12;
  const bool gmode = (tm >= 4) && (tm < 8);
  const int t = threadIdx.x, lane = t & 63, wid = t >> 6;
  const int wr = wid >> 1, wc = wid & 1, lr = lane & 15, lq = lane >> 4;

  // staging: 4 chunks each; chunk q covers rows q*32..q*32+31, 8 slots/row
  const int srow = t >> 3, sslot = t & 7;      // srow 0..31 within chunk
  int arow_g[4]; size_t bxr_g[4]; int ksw[4];
#pragma unroll
  for (int q = 0; q < 4; ++q) {
    const int row = q * 32 + srow;             // 0..127
    ksw[q] = ((sslot ^ (row & 7)) << 3);       // swizzled k offset (u16)
    arow_g[q] = tm * 128 + row;                // W row (f/g/h contiguous)
    const int jg = tn * 128 + row;
    bxr_g[q] = gmode ? ((size_t)(jg & 255) * 256 + (jg >> 8)) : (size_t)jg;
  }

  // fragment read bases: row*64 u16 (128 B rows), XOR slot = (kk*4+lq)^(row&7)
  int offA[4], a7[4], offB[4], b7[4];
#pragma unroll
  for (int mi = 0; mi < 4; ++mi) {
    const int rowA = wr * 64 + mi * 16 + lr;
    offA[mi] = rowA * 64; a7[mi] = rowA & 7;
  }
#pragma unroll
  for (int ni = 0; ni < 4; ++ni) {
    const int rowB = wc * 64 + ni * 16 + lr;
    offB[ni] = rowB * 64; b7[ni] = rowB & 7;
  }

  f32x4 acc[4][4] = {};

  for (int k0 = 0; k0 < 512; k0 += 64) {
#pragma unroll
    for (int q = 0; q < 4; ++q) {
      gload16(W16 + (size_t)arow_g[q] * 512 + k0 + ksw[q], (char*)sA + q * 4096 + t * 16);
      gload16(x16 + bxr_g[q] * 512 + k0 + ksw[q],          (char*)sB + q * 4096 + t * 16);
    }
    __syncthreads();
#pragma unroll
    for (int kk = 0; kk < 2; ++kk) {
      half8 a[4], b[4];
#pragma unroll
      for (int mi = 0; mi < 4; ++mi)
        a[mi] = *(const half8*)(sA + offA[mi] + (((kk * 4 + lq) ^ a7[mi]) << 3));
#pragma unroll
      for (int ni = 0; ni < 4; ++ni)
        b[ni] = *(const half8*)(sB + offB[ni] + (((kk * 4 + lq) ^ b7[ni]) << 3));
#pragma unroll
      for (int mi = 0; mi < 4; ++mi)
#pragma unroll
        for (int ni = 0; ni < 4; ++ni)
          acc[mi][ni] = MFMAH(a[mi], b[ni], acc[mi][ni], 0, 0, 0);
    }
    __syncthreads();
  }

  const int cls = tm >> 2;                     // 0:f 1:g 2:h
  u16* dst = (cls == 0) ? fb : (cls == 1) ? gTb : hb;
  const int rbase = (tm & 3) * 128 + wr * 64;
  const int cbase = tn * 128 + wc * 64;
#pragma unroll
  for (int mi = 0; mi < 4; ++mi)
#pragma unroll
    for (int ni = 0; ni < 4; ++ni) {
      const int r0 = rbase + mi * 16 + lq * 4;
      const int cc = cbase + ni * 16 + lr;
#pragma unroll
      for (int r = 0; r < 4; ++r)
        dst[(size_t)(r0 + r) * 65536 + cc] = f2h(acc[mi][ni][r]);
    }
}

// ---------------------------------------------------------------------------
// scores: per (c, jt): S = f[c](256 x 256) @ gT[c][jt](128 x 256)^T, fp16.
// Block owns FULL softmax columns -> writes normalized PT[c][j][i] fp16.
// ---------------------------------------------------------------------------
__global__ __launch_bounds__(512)
void scores_kernel(const u16* __restrict__ fb, const u16* __restrict__ gTb,
                   u16* __restrict__ Pt)
{
  __shared__ u16 sA[8192];                     // 16 KB: 256 rows x 32 k
  __shared__ u16 sB[4096];                     // 8 KB: 128 rows x 32 k
  __shared__ float cmax[512], csum[512];
  const int bid = blockIdx.x;
  const int xcd = bid & 7, i2 = bid >> 3;      // 1024 = 8 x (64 c x 2 jt)
  const int c = xcd * 64 + (i2 >> 1), jt = i2 & 1;
  const size_t cb = (size_t)c * 65536;
  const int t = threadIdx.x, lane = t & 63, wid = t >> 6;
  const int wr = wid >> 1, wc = wid & 1, lr = lane & 15, lq = lane >> 4;

  const int arow0 = t >> 2, arow1 = 128 + (t >> 2);
  const int aks0 = (((t & 3) ^ ((arow0 >> 1) & 3)) << 3);
  const int aks1 = (((t & 3) ^ ((arow1 >> 1) & 3)) << 3);
  const int brow = t >> 2;
  const int bks  = (((t & 3) ^ ((brow >> 1) & 3)) << 3);

  int offA[4], offB[4];
#pragma unroll
  for (int mi = 0; mi < 4; ++mi) {
    const int rowA = wr * 64 + mi * 16 + lr;
    offA[mi] = rowA * 32 + ((lq ^ ((rowA >> 1) & 3)) << 3);
  }
#pragma unroll
  for (int ni = 0; ni < 4; ++ni) {
    const int rowB = wc * 64 + ni * 16 + lr;
    offB[ni] = rowB * 32 + ((lq ^ ((rowB >> 1) & 3)) << 3);
  }

  f32x4 acc[4][4] = {};

  for (int k0 = 0; k0 < 256; k0 += 32) {
    gload16(fb + cb + (size_t)arow0 * 256 + k0 + aks0, (char*)sA + t * 16);
    gload16(fb + cb + (size_t)arow1 * 256 + k0 + aks1, (char*)sA + 8192 + t * 16);
    gload16(gTb + cb + (size_t)(jt * 128 + brow) * 256 + k0 + bks, (char*)sB + t * 16);
    __syncthreads();
    half8 a[4], b[4];
#pragma unroll
    for (int mi = 0; mi < 4; ++mi) a[mi] = *(const half8*)(sA + offA[mi]);
#pragma unroll
    for (int ni = 0; ni < 4; ++ni) b[ni] = *(const half8*)(sB + offB[ni]);
#pragma unroll
    for (int mi = 0; mi < 4; ++mi)
#pragma unroll
      for (int ni = 0; ni < 4; ++ni)
        acc[mi][ni] = MFMAH(a[mi], b[ni], acc[mi][ni], 0, 0, 0);
    __syncthreads();
  }

  // ---- full-column softmax over i (rows span wr,mi,lq,r), per column
#pragma unroll
  for (int ni = 0; ni < 4; ++ni) {
    const int col = wc * 64 + ni * 16 + lr;
    float m = -3.4e38f;
#pragma unroll
    for (int mi = 0; mi < 4; ++mi) {
      f32x4 a = acc[mi][ni];
      m = fmaxf(m, fmaxf(fmaxf(a[0], a[1]), fmaxf(a[2], a[3])));
    }
    m = fmaxf(m, __shfl_xor(m, 16));
    m = fmaxf(m, __shfl_xor(m, 32));
    cmax[wr * 128 + col] = m;
  }
  __syncthreads();
#pragma unroll
  for (int ni = 0; ni < 4; ++ni) {
    const int col = wc * 64 + ni * 16 + lr;
    const float M = fmaxf(fmaxf(cmax[col], cmax[128 + col]),
                          fmaxf(cmax[256 + col], cmax[384 + col]));
    float s = 0.f;
#pragma unroll
    for (int mi = 0; mi < 4; ++mi)
#pragma unroll
      for (int r = 0; r < 4; ++r) {
        float e = __expf(acc[mi][ni][r] - M);
        acc[mi][ni][r] = e; s += e;
      }
    s += __shfl_xor(s, 16);
    s += __shfl_xor(s, 32);
    csum[wr * 128 + col] = s;
  }
  __syncthreads();
#pragma unroll
  for (int ni = 0; ni < 4; ++ni) {
    const int col = wc * 64 + ni * 16 + lr;
    const float rs = 1.f / (csum[col] + csum[128 + col] + csum[256 + col] + csum[384 + col]);
    const int j = jt * 128 + col;
#pragma unroll
    for (int mi = 0; mi < 4; ++mi) {
      u16x4 w = { f2h(acc[mi][ni][0] * rs), f2h(acc[mi][ni][1] * rs),
                  f2h(acc[mi][ni][2] * rs), f2h(acc[mi][ni][3] * rs) };
      *(u16x4*)(Pt + cb + (size_t)j * 256 + wr * 64 + mi * 16 + lq * 4) = w;
    }
  }
}

// ---------------------------------------------------------------------------
// attn: out[c,a,j] = x[c,a,j] + sum_i h[c,a,i] * PT[c,j,i]. fp16 MFMA.
// 256x128 tile (2 blocks/channel), 512 thr = 8 waves (4M x 2N).
// ---------------------------------------------------------------------------
__global__ __launch_bounds__(512, 4)
void attn_kernel(const u16* __restrict__ hb, const u16* __restrict__ Pt,
                 const float* __restrict__ x, float* __restrict__ out)
{
  __shared__ u16 sA[8192], sB[4096];           // 16 KB + 8 KB
  const int bid = blockIdx.x;
  const int xcd = bid & 7, i2 = bid >> 3;      // 1024 = 8 x (64 c x 2 tn)
  const int c = xcd * 64 + (i2 >> 1), tn = i2 & 1;
  const size_t cb = (size_t)c * 65536;
  const int t = threadIdx.x, lane = t & 63, wid = t >> 6;
  const int wr = wid >> 1, wc = wid & 1, lr = lane & 15, lq = lane >> 4;

  const int ar0 = t >> 2, ar1 = 128 + (t >> 2);
  const int aks0 = (((t & 3) ^ ((ar0 >> 1) & 3)) << 3);
  const int aks1 = (((t & 3) ^ ((ar1 >> 1) & 3)) << 3);
  const int br = t >> 2;
  const int bks = (((t & 3) ^ ((br >> 1) & 3)) << 3);

  int offA[4], offB[4];
#pragma unroll
  for (int mi = 0; mi < 4; ++mi) {
    const int rowA = wr * 64 + mi * 16 + lr;   // 0..255
    offA[mi] = rowA * 32 + ((lq ^ ((rowA >> 1) & 3)) << 3);
  }
#pragma unroll
  for (int ni = 0; ni < 4; ++ni) {
    const int rowB = wc * 64 + ni * 16 + lr;   // 0..127
    offB[ni] = rowB * 32 + ((lq ^ ((rowB >> 1) & 3)) << 3);
  }

  f32x4 acc[4][4] = {};

  for (int k0 = 0; k0 < 256; k0 += 32) {
    gload16(hb + cb + (size_t)ar0 * 256 + k0 + aks0, (char*)sA + t * 16);
    gload16(hb + cb + (size_t)ar1 * 256 + k0 + aks1, (char*)sA + 8192 + t * 16);
    gload16(Pt + cb + (size_t)(tn * 128 + br) * 256 + k0 + bks, (char*)sB + t * 16);
    __syncthreads();
    half8 a[4], b[4];
#pragma unroll
    for (int mi = 0; mi < 4; ++mi) a[mi] = *(const half8*)(sA + offA[mi]);
#pragma unroll
    for (int ni = 0; ni < 4; ++ni) b[ni] = *(const half8*)(sB + offB[ni]);
#pragma unroll
    for (int mi = 0; mi < 4; ++mi)
#pragma unroll
      for (int ni = 0; ni < 4; ++ni)
        acc[mi][ni] = MFMAH(a[mi], b[ni], acc[mi][ni], 0, 0, 0);
    __syncthreads();
  }

  const float* Xc = x + cb;
  float* Oc = out + cb;
  const int rbase = wr * 64;                   // rows 0..255
  const int cbase = tn * 128 + wc * 64;        // cols 0..255
#pragma unroll
  for (int mi = 0; mi < 4; ++mi)
#pragma unroll
    for (int ni = 0; ni < 4; ++ni) {
      const int r0 = rbase + mi * 16 + lq * 4, cc = cbase + ni * 16 + lr;
#pragma unroll
      for (int r = 0; r < 4; ++r) {
        const size_t idx = (size_t)(r0 + r) * 256 + cc;
        Oc[idx] = Xc[idx] + acc[mi][ni][r];
      }
    }
}

// ---------------------------------------------------------------------------
extern "C" void kernel_launch(void* const* d_in, const int* in_sizes, int n_in,
                              void* d_out, int out_size, void* d_ws, size_t ws_size,
                              hipStream_t stream)
{
  (void)in_sizes; (void)n_in; (void)out_size; (void)ws_size;
  const float* x  = (const float*)d_in[0];
  const float* Wf = (const float*)d_in[1];
  const float* Wg = (const float*)d_in[2];
  const float* Wh = (const float*)d_in[3];
  float* out = (float*)d_out;
  char*  ws  = (char*)d_ws;

  // ws: [x16 64Mi][gT16 64Mi][h16 64Mi]; f16 lives in d_out's first 64 MiB.
  u16* x16  = (u16*)ws;
  u16* gT16 = (u16*)(ws + 67108864);
  u16* h16  = (u16*)(ws + 134217728);
  u16* f16  = (u16*)d_out;
  u16* Pt   = x16;   // PT overwrites x16 after conv_fgh

  dim3 blk(256, 1, 1);
  prep_w       <<<dim3(1536, 1, 1), blk, 0, stream>>>(Wf, Wg, Wh);
  prep_x       <<<dim3(2048, 1, 1), blk, 0, stream>>>(x, x16);
  conv_fgh     <<<dim3(6144, 1, 1), blk, 0, stream>>>(x16, f16, gT16, h16);
  scores_kernel<<<dim3(1024, 1, 1), dim3(512, 1, 1), 0, stream>>>(f16, gT16, Pt);
  attn_kernel  <<<dim3(1024, 1, 1), dim3(512, 1, 1), 0, stream>>>(h16, Pt, x, out);
}